// Round 8
// baseline (50.426 us; speedup 1.0000x reference)
//
#include <hip/hip_runtime.h>

#define NROWS 4096
#define DIM   512
#define MARGIN 0.3f

typedef _Float16 f16;
typedef _Float16 f16x8 __attribute__((ext_vector_type(8)));
typedef float    f32x16 __attribute__((ext_vector_type(16)));

// ---------------- prep: norms + fp32->fp16 tiled convert + hp/hn init ----------------
// Xh layout: tile (R,K0), R=row/128 in [0,32), K0=k/32 in [0,16).
// Tile = 512 units of 16B: unit u = rg*64 + c*16 + r (rg=(row%128)/16, r=row%16)
// element (row, k=K0*32+c*8+j) at half index (tile*512+u)*8 + j.
__global__ void prep_kernel(const float* __restrict__ X,
                            float* __restrict__ norms, f16* __restrict__ Xh,
                            unsigned* __restrict__ hp, unsigned* __restrict__ hn) {
    int t = threadIdx.x;
    int wave = t >> 6, lane = t & 63;
    int row  = blockIdx.x * 4 + wave;
    const float4* p = (const float4*)(X + (size_t)row * DIM + lane * 8);
    float4 a = p[0], b = p[1];
    float s = a.x*a.x + a.y*a.y + a.z*a.z + a.w*a.w
            + b.x*b.x + b.y*b.y + b.z*b.z + b.w*b.w;
    #pragma unroll
    for (int o = 32; o; o >>= 1) s += __shfl_xor(s, o);
    if (lane == 0) norms[row] = s;

    f16x8 h;
    h[0] = (f16)a.x; h[1] = (f16)a.y; h[2] = (f16)a.z; h[3] = (f16)a.w;
    h[4] = (f16)b.x; h[5] = (f16)b.y; h[6] = (f16)b.z; h[7] = (f16)b.w;
    int K0 = lane >> 2, c = lane & 3;
    int R = row >> 7, rw = row & 127, rg = rw >> 4, r = rw & 15;
    size_t unit = (size_t)(R * 16 + K0) * 512 + rg * 64 + c * 16 + r;
    *(f16x8*)(Xh + unit * 8) = h;

    int g = blockIdx.x * 256 + t;
    if (g < NROWS) { hp[g] = 0u; hn[g] = 0x7f800000u; }
}

__device__ inline void gload_lds16(const f16* g, f16* l) {
    __builtin_amdgcn_global_load_lds(
        (const __attribute__((address_space(1))) void*)g,
        (__attribute__((address_space(3))) void*)l, 16, 0, 0);
}

// stage one 128x32 A-tile + B-tile pair into buf; wave w covers units [qb, qb+256)
__device__ inline void stage_tile(const f16* __restrict__ At, const f16* __restrict__ Bt,
                                  f16* buf, int qb, int lane) {
    const f16* base = (qb < 512) ? (At + (size_t)qb * 8) : (Bt + (size_t)(qb - 512) * 8);
    #pragma unroll
    for (int c2 = 0; c2 < 4; ++c2)
        gload_lds16(base + (size_t)(c2 * 64 + lane) * 8, buf + (size_t)(qb + c2 * 64) * 8);
}

// ---------------- MFMA fused GEMM + masked row/col max-min ----------------
// Lower-triangle grid (by <= bx); 128x128 tile, 4 waves (2x2 of 64x64).
// 32x32x16 MFMA: per wave 2x2 fragments of 32x32, 8 MFMA per K-step (BK=32).
// Triple-buffered LDS, ONE barrier per K-step, counted vmcnt (4 steady).
__global__ __launch_bounds__(256, 3) void mfma_dist_kernel(
        const f16* __restrict__ Xh, const int* __restrict__ labels,
        const float* __restrict__ norms,
        unsigned* __restrict__ hp, unsigned* __restrict__ hn) {
    __shared__ __align__(16) f16 S[3 * 8192];

    const int t    = threadIdx.x;
    const int lane = t & 63, w = t >> 6;
    const int l15  = lane & 15;
    const int l31  = lane & 31;
    const int hi   = lane >> 5;       // 0/1
    const int g16  = l31 >> 4;        // which 16-row group within 32

    // XCD chunk swizzle: 528 = 8 * 66 exactly -> bijective remap
    int bthw = blockIdx.x;
    int bt = (bthw & 7) * 66 + (bthw >> 3);

    // linear bt -> (by <= bx)
    int bx = (int)((sqrtf(8.0f * bt + 1.0f) - 1.0f) * 0.5f);
    while ((bx + 1) * (bx + 2) / 2 <= bt) ++bx;
    while (bx * (bx + 1) / 2 > bt) --bx;
    int by = bt - bx * (bx + 1) / 2;

    const int wr = w >> 1, wc = w & 1;
    const int qb = w * 256;

    const f16* Abase = Xh + (size_t)(by * 16) * 4096;
    const f16* Bbase = Xh + (size_t)(bx * 16) * 4096;

    f32x16 acc[2][2];
    #pragma unroll
    for (int m = 0; m < 2; ++m)
        #pragma unroll
        for (int n = 0; n < 2; ++n)
            #pragma unroll
            for (int i = 0; i < 16; ++i) acc[m][n][i] = 0.f;

    // prologue: tiles 0,1 in flight (8 loads/wave)
    stage_tile(Abase,        Bbase,        S,        qb, lane);
    stage_tile(Abase + 4096, Bbase + 4096, S + 8192, qb, lane);
    __builtin_amdgcn_sched_barrier(0);

    #pragma unroll
    for (int kt = 0; kt < 16; ++kt) {
        f16* cur = S + (kt % 3) * 8192;
        if (kt == 15) asm volatile("s_waitcnt vmcnt(0)" ::: "memory");
        else          asm volatile("s_waitcnt vmcnt(4)" ::: "memory");
        __builtin_amdgcn_sched_barrier(0);
        __builtin_amdgcn_s_barrier();      // all waves' tile-kt data in LDS
        __builtin_amdgcn_sched_barrier(0);

        if (kt + 2 < 16)                   // slot (kt+2)%3 consumed at step kt-1
            stage_tile(Abase + (size_t)(kt + 2) * 4096,
                       Bbase + (size_t)(kt + 2) * 4096,
                       S + ((kt + 2) % 3) * 8192, qb, lane);
        __builtin_amdgcn_sched_barrier(0);

        // fragment loads: lane holds 8 contiguous k at k = ks*16 + hi*8,
        // row/col = frag_base + l31.  unit = rg*64 + c*16 + r.
        f16x8 af[2][2], bf[2][2];
        #pragma unroll
        for (int m = 0; m < 2; ++m)
            #pragma unroll
            for (int ks = 0; ks < 2; ++ks)
                af[m][ks] = *(const f16x8*)&cur[
                    (size_t)(((wr * 4 + m * 2 + g16) * 64) + (ks * 2 + hi) * 16 + l15) * 8];
        #pragma unroll
        for (int n = 0; n < 2; ++n)
            #pragma unroll
            for (int ks = 0; ks < 2; ++ks)
                bf[n][ks] = *(const f16x8*)&cur[
                    (size_t)(512 + ((wc * 4 + n * 2 + g16) * 64) + (ks * 2 + hi) * 16 + l15) * 8];
        #pragma unroll
        for (int ks = 0; ks < 2; ++ks)
            #pragma unroll
            for (int m = 0; m < 2; ++m)
                #pragma unroll
                for (int n = 0; n < 2; ++n)
                    acc[m][n] = __builtin_amdgcn_mfma_f32_32x32x16_f16(
                        af[m][ks], bf[n][ks], acc[m][n], 0, 0, 0);
        __builtin_amdgcn_sched_barrier(0);
    }

    // ---- epilogue: sq = ni + nj - 2*dot, masked row & col reduce ----
    // C/D layout (32x32): col = lane&31, row = (reg&3) + 8*(reg>>2) + 4*(lane>>5)
    const int wrow = by * 128 + wr * 64;
    const int wcol = bx * 128 + wc * 64;
    const float FINF = __uint_as_float(0x7f800000u);

    int lj[2]; float nj[2];
    #pragma unroll
    for (int n = 0; n < 2; ++n) {
        int gc = wcol + n * 32 + l31; lj[n] = labels[gc]; nj[n] = norms[gc];
    }

    float cp[2], cn_[2];
    #pragma unroll
    for (int n = 0; n < 2; ++n) { cp[n] = 0.f; cn_[n] = FINF; }

    #pragma unroll
    for (int m = 0; m < 2; ++m) {
        #pragma unroll
        for (int i = 0; i < 16; ++i) {
            int ra   = (i & 3) + 8 * (i >> 2);
            int grow = wrow + m * 32 + ra + 4 * hi;
            int   lr = labels[grow];
            float nr = norms[grow];
            float rp = 0.f, rn = FINF;
            #pragma unroll
            for (int n = 0; n < 2; ++n) {
                float sq = fmaxf(fmaf(-2.f, acc[m][n][i], nr + nj[n]), 0.f);
                bool same = (lr == lj[n]);
                rp = same ? fmaxf(rp, sq) : rp;
                rn = same ? rn : fminf(rn, sq);
                cp[n]  = same ? fmaxf(cp[n], sq) : cp[n];
                cn_[n] = same ? cn_[n] : fminf(cn_[n], sq);
            }
            // reduce across the 32 cols held in this half-wave
            #pragma unroll
            for (int o = 16; o; o >>= 1) {
                rp = fmaxf(rp, __shfl_xor(rp, o));
                rn = fminf(rn, __shfl_xor(rn, o));
            }
            if (l31 == 0) {
                atomicMax(&hp[grow], __float_as_uint(rp));
                atomicMin(&hn[grow], __float_as_uint(rn));
            }
        }
    }
    #pragma unroll
    for (int n = 0; n < 2; ++n) {
        float p = fmaxf(cp[n],  __shfl_xor(cp[n],  32));
        float q = fminf(cn_[n], __shfl_xor(cn_[n], 32));
        if (hi == 0) {
            int gc = wcol + n * 32 + l31;
            atomicMax(&hp[gc], __float_as_uint(p));
            atomicMin(&hn[gc], __float_as_uint(q));
        }
    }
}

// ---------------- fp32 fallback path (ws too small for Xh) ----------------
__global__ void norms_init_kernel(const float* __restrict__ X,
                                  float* __restrict__ norms,
                                  unsigned* __restrict__ hp, unsigned* __restrict__ hn) {
    int wave = threadIdx.x >> 6;
    int lane = threadIdx.x & 63;
    int row  = blockIdx.x * 4 + wave;
    const float4* xr = (const float4*)(X + (size_t)row * DIM);
    float4 a = xr[lane];
    float4 b = xr[lane + 64];
    float s = a.x*a.x + a.y*a.y + a.z*a.z + a.w*a.w
            + b.x*b.x + b.y*b.y + b.z*b.z + b.w*b.w;
    #pragma unroll
    for (int o = 32; o; o >>= 1) s += __shfl_xor(s, o);
    if (lane == 0) norms[row] = s;
    int g = blockIdx.x * 256 + threadIdx.x;
    if (g < NROWS) { hp[g] = 0u; hn[g] = 0x7f800000u; }
}

#define BK  32
#define PAD 68
__global__ __launch_bounds__(256) void dist_fp32_kernel(
        const float* __restrict__ X, const int* __restrict__ labels,
        const float* __restrict__ norms,
        unsigned* __restrict__ hp, unsigned* __restrict__ hn) {
    __shared__ __align__(16) float As[BK][PAD];
    __shared__ __align__(16) float Bs[BK][PAD];
    const int t  = threadIdx.x;
    const int tx = t & 15, ty = t >> 4;
    const int row0 = blockIdx.y * 64, col0 = blockIdx.x * 64;

    float acc[4][4] = {};
    for (int k0 = 0; k0 < DIM; k0 += BK) {
        #pragma unroll
        for (int l = 0; l < 2; ++l) {
            int idx = t + l * 256;
            int r = idx >> 3, fc = idx & 7;
            float4 va = *(const float4*)(X + (size_t)(row0 + r) * DIM + k0 + fc * 4);
            float4 vb = *(const float4*)(X + (size_t)(col0 + r) * DIM + k0 + fc * 4);
            As[fc*4+0][r] = va.x; As[fc*4+1][r] = va.y;
            As[fc*4+2][r] = va.z; As[fc*4+3][r] = va.w;
            Bs[fc*4+0][r] = vb.x; Bs[fc*4+1][r] = vb.y;
            Bs[fc*4+2][r] = vb.z; Bs[fc*4+3][r] = vb.w;
        }
        __syncthreads();
        #pragma unroll
        for (int kk = 0; kk < BK; ++kk) {
            float4 a = *(const float4*)&As[kk][ty * 4];
            float4 b = *(const float4*)&Bs[kk][tx * 4];
            float av[4] = {a.x, a.y, a.z, a.w};
            float bv[4] = {b.x, b.y, b.z, b.w};
            #pragma unroll
            for (int m = 0; m < 4; ++m)
                #pragma unroll
                for (int n = 0; n < 4; ++n)
                    acc[m][n] = fmaf(av[m], bv[n], acc[m][n]);
        }
        __syncthreads();
    }
    int li[4], lj[4]; float ni[4], nj[4];
    #pragma unroll
    for (int m = 0; m < 4; ++m) {
        int gi = row0 + ty * 4 + m; li[m] = labels[gi]; ni[m] = norms[gi];
    }
    #pragma unroll
    for (int n = 0; n < 4; ++n) {
        int gj = col0 + tx * 4 + n; lj[n] = labels[gj]; nj[n] = norms[gj];
    }
    #pragma unroll
    for (int m = 0; m < 4; ++m) {
        float pmax = 0.0f;
        float nmin = __uint_as_float(0x7f800000u);
        #pragma unroll
        for (int n = 0; n < 4; ++n) {
            float sq = fmaxf(ni[m] + nj[n] - 2.0f * acc[m][n], 0.0f);
            if (li[m] == lj[n]) pmax = fmaxf(pmax, sq);
            else                nmin = fminf(nmin, sq);
        }
        #pragma unroll
        for (int o = 8; o; o >>= 1) {
            pmax = fmaxf(pmax, __shfl_xor(pmax, o));
            nmin = fminf(nmin, __shfl_xor(nmin, o));
        }
        if (tx == 0) {
            int gi = row0 + ty * 4 + m;
            atomicMax(&hp[gi], __float_as_uint(pmax));
            atomicMin(&hn[gi], __float_as_uint(nmin));
        }
    }
}

// ---------------- finalize: hist in LDS + per-row loss + full reduce ----------------
__global__ __launch_bounds__(1024) void finalize_kernel(
        const unsigned* __restrict__ hp, const unsigned* __restrict__ hn,
        const int* __restrict__ labels, float* __restrict__ out) {
    __shared__ int hist[256];
    __shared__ float wsum[16];
    int t = threadIdx.x;
    if (t < 256) hist[t] = 0;
    __syncthreads();
    int4 lab = ((const int4*)labels)[t];
    atomicAdd(&hist[lab.x], 1); atomicAdd(&hist[lab.y], 1);
    atomicAdd(&hist[lab.z], 1); atomicAdd(&hist[lab.w], 1);
    __syncthreads();
    uint4 hp4 = ((const uint4*)hp)[t];
    uint4 hn4 = ((const uint4*)hn)[t];
    int      lv[4]  = {lab.x, lab.y, lab.z, lab.w};
    unsigned hpv[4] = {hp4.x, hp4.y, hp4.z, hp4.w};
    unsigned hnv[4] = {hn4.x, hn4.y, hn4.z, hn4.w};
    float v = 0.f;
    #pragma unroll
    for (int j = 0; j < 4; ++j) {
        float hpd = sqrtf(__uint_as_float(hpv[j]));
        float hnd = sqrtf(__uint_as_float(hnv[j]));   // may be +inf
        if (hist[lv[j]] > 1) v += fmaxf(hpd - hnd + MARGIN, 0.f);
    }
    #pragma unroll
    for (int o = 32; o; o >>= 1) v += __shfl_xor(v, o);
    int lane = t & 63, wv = t >> 6;
    if (lane == 0) wsum[wv] = v;
    __syncthreads();
    if (t == 0) {
        float s = 0.f;
        #pragma unroll
        for (int i = 0; i < 16; ++i) s += wsum[i];
        out[0] = s / (float)NROWS;
    }
}

extern "C" void kernel_launch(void* const* d_in, const int* in_sizes, int n_in,
                              void* d_out, int out_size, void* d_ws, size_t ws_size,
                              hipStream_t stream) {
    const float* X      = (const float*)d_in[0];
    const int*   labels = (const int*)d_in[1];
    float* ws = (float*)d_ws;
    // ws (floats): norms[4096] | hp[4096] | hn[4096] | pad -> 64KB | Xh (4MB)
    float*    norms = ws;
    unsigned* hp    = (unsigned*)(ws + 4096);
    unsigned* hn    = (unsigned*)(ws + 8192);
    f16*      Xh    = (f16*)((char*)d_ws + 65536);
    float*    out   = (float*)d_out;

    const size_t need = 65536 + (size_t)NROWS * DIM * sizeof(f16);

    if (ws_size >= need) {
        hipLaunchKernelGGL(prep_kernel,      dim3(NROWS/4), dim3(256), 0, stream,
                           X, norms, Xh, hp, hn);
        hipLaunchKernelGGL(mfma_dist_kernel, dim3(528),     dim3(256), 0, stream,
                           Xh, labels, norms, hp, hn);
    } else {
        hipLaunchKernelGGL(norms_init_kernel, dim3(NROWS/4), dim3(256), 0, stream, X, norms, hp, hn);
        hipLaunchKernelGGL(dist_fp32_kernel,  dim3(64, 64),  dim3(256), 0, stream, X, labels, norms, hp, hn);
    }
    hipLaunchKernelGGL(finalize_kernel, dim3(1), dim3(1024), 0, stream, hp, hn, labels, out);
}

// Round 9
// 38.756 us; speedup vs baseline: 1.3011x; 1.3011x over previous
//
#include <hip/hip_runtime.h>

#define NROWS 4096
#define DIM   512
#define MARGIN 0.3f

typedef _Float16 f16;
typedef _Float16 f16x8 __attribute__((ext_vector_type(8)));
typedef float    f32x4 __attribute__((ext_vector_type(4)));

// ---------------- prep: norms + fp32->fp16 tiled convert + hp/hn init ----------------
// Xh layout: tile (R,K0), R=row/128 in [0,32), K0=k/32 in [0,16).
// Tile = 512 units of 16B: unit u = rg*64 + c*16 + r (rg=(row%128)/16, r=row%16)
// element (row, k=K0*32+c*8+j) at half index (tile*512+u)*8 + j.
__global__ void prep_kernel(const float* __restrict__ X,
                            float* __restrict__ norms, f16* __restrict__ Xh,
                            unsigned* __restrict__ hp, unsigned* __restrict__ hn) {
    int t = threadIdx.x;
    int wave = t >> 6, lane = t & 63;
    int row  = blockIdx.x * 4 + wave;
    const float4* p = (const float4*)(X + (size_t)row * DIM + lane * 8);
    float4 a = p[0], b = p[1];
    float s = a.x*a.x + a.y*a.y + a.z*a.z + a.w*a.w
            + b.x*b.x + b.y*b.y + b.z*b.z + b.w*b.w;
    #pragma unroll
    for (int o = 32; o; o >>= 1) s += __shfl_xor(s, o);
    if (lane == 0) norms[row] = s;

    f16x8 h;
    h[0] = (f16)a.x; h[1] = (f16)a.y; h[2] = (f16)a.z; h[3] = (f16)a.w;
    h[4] = (f16)b.x; h[5] = (f16)b.y; h[6] = (f16)b.z; h[7] = (f16)b.w;
    int K0 = lane >> 2, c = lane & 3;
    int R = row >> 7, rw = row & 127, rg = rw >> 4, r = rw & 15;
    size_t unit = (size_t)(R * 16 + K0) * 512 + rg * 64 + c * 16 + r;
    *(f16x8*)(Xh + unit * 8) = h;

    int g = blockIdx.x * 256 + t;
    if (g < NROWS) { hp[g] = 0u; hn[g] = 0x7f800000u; }
}

__device__ inline void gload_lds16(const f16* g, f16* l) {
    __builtin_amdgcn_global_load_lds(
        (const __attribute__((address_space(1))) void*)g,
        (__attribute__((address_space(3))) void*)l, 16, 0, 0);
}

// stage one 64x32 A-half-tile + 128x32 B-tile into buf (768 units of 16B);
// wave w covers units [w*192, w*192+192) -> 3 gloads/lane.
// buf layout: A units 0..255 (rg*64+c*16+r, rg local 0..3), B units 256..767.
__device__ inline void stage_half(const f16* __restrict__ Ab, const f16* __restrict__ Bb,
                                  f16* buf, int qb, int lane) {
    #pragma unroll
    for (int c2 = 0; c2 < 3; ++c2) {
        int q = qb + c2 * 64 + lane;
        const f16* src = (q < 256) ? (Ab + (size_t)q * 8) : (Bb + (size_t)(q - 256) * 8);
        gload_lds16(src, buf + (size_t)(qb + c2 * 64) * 8);
    }
}

// ---------------- MFMA fused GEMM + masked row/col max-min ----------------
// Half-tile grid: 1056 blocks of 64(rows)x128(cols), lower-triangle coverage
// (col-tile bx <= row-half by2/2). 4 waves (2x2), per wave 32x64 out = 2x4
// frags of 16x16x32, 8 MFMA/K-step. Triple-buffered LDS (12KB/step), ONE
// barrier per K-step, counted vmcnt (3 steady), setprio around MFMA cluster.
__global__ __launch_bounds__(256, 4) void mfma_dist_kernel(
        const f16* __restrict__ Xh, const int* __restrict__ labels,
        const float* __restrict__ norms,
        unsigned* __restrict__ hp, unsigned* __restrict__ hn) {
    __shared__ __align__(16) f16 S[3 * 6144];

    const int t    = threadIdx.x;
    const int lane = t & 63, w = t >> 6;
    const int l15  = lane & 15, l4 = lane >> 4;

    // XCD chunk swizzle: 1056 = 8 * 132 exactly -> bijective remap
    int bthw = blockIdx.x;
    int bt = (bthw & 7) * 132 + (bthw >> 3);

    // bt -> (by2 in [0,64) row-half, bx in [0,32) col-tile), bx <= by2/2.
    // cum(2a) = a(a+1), cum(2a+1) = (a+1)^2.
    int s = (int)sqrtf((float)bt);
    while ((s + 1) * (s + 1) <= bt) ++s;
    while (s * s > bt) --s;
    int by2, bx;
    if (bt < s * (s + 1)) { by2 = 2 * s - 1; bx = bt - s * s; }
    else                  { by2 = 2 * s;     bx = bt - s * (s + 1); }

    const int wr = w >> 1, wc = w & 1;
    const int qb = w * 192;

    const int R = by2 >> 1, half = by2 & 1;
    const f16* Ab = Xh + (size_t)(R * 16) * 4096 + half * 2048;   // 64-row half panel
    const f16* Bb = Xh + (size_t)(bx * 16) * 4096;

    f32x4 zero = {0.f, 0.f, 0.f, 0.f};
    f32x4 acc[2][4];
    #pragma unroll
    for (int m = 0; m < 2; ++m)
        #pragma unroll
        for (int n = 0; n < 4; ++n) acc[m][n] = zero;

    // prologue: tiles 0,1 in flight (6 loads/wave)
    stage_half(Ab,        Bb,        S,        qb, lane);
    stage_half(Ab + 4096, Bb + 4096, S + 6144, qb, lane);
    __builtin_amdgcn_sched_barrier(0);

    #pragma unroll
    for (int kt = 0; kt < 16; ++kt) {
        f16* cur = S + (kt % 3) * 6144;
        if (kt == 15) asm volatile("s_waitcnt vmcnt(0)" ::: "memory");
        else          asm volatile("s_waitcnt vmcnt(3)" ::: "memory");
        __builtin_amdgcn_sched_barrier(0);
        __builtin_amdgcn_s_barrier();      // all waves' tile-kt data in LDS
        __builtin_amdgcn_sched_barrier(0);

        if (kt + 2 < 16)                   // slot (kt+2)%3 consumed at step kt-1
            stage_half(Ab + (size_t)(kt + 2) * 4096,
                       Bb + (size_t)(kt + 2) * 4096,
                       S + ((kt + 2) % 3) * 6144, qb, lane);
        __builtin_amdgcn_sched_barrier(0);

        f16x8 af[2], bf[4];
        #pragma unroll
        for (int m = 0; m < 2; ++m)
            af[m] = *(const f16x8*)&cur[(size_t)((wr * 2 + m) * 64 + l4 * 16 + l15) * 8];
        #pragma unroll
        for (int n = 0; n < 4; ++n)
            bf[n] = *(const f16x8*)&cur[(size_t)(256 + (wc * 4 + n) * 64 + l4 * 16 + l15) * 8];
        __builtin_amdgcn_s_setprio(1);
        #pragma unroll
        for (int m = 0; m < 2; ++m)
            #pragma unroll
            for (int n = 0; n < 4; ++n)
                acc[m][n] = __builtin_amdgcn_mfma_f32_16x16x32_f16(af[m], bf[n], acc[m][n], 0, 0, 0);
        __builtin_amdgcn_s_setprio(0);
        __builtin_amdgcn_sched_barrier(0);
    }

    // ---- epilogue: sq = ni + nj - 2*dot, masked row & col reduce ----
    const int wrow = by2 * 64 + wr * 32;
    const int wcol = bx * 128 + wc * 64;
    const float FINF = __uint_as_float(0x7f800000u);

    int lj[4]; float nj[4];
    #pragma unroll
    for (int n = 0; n < 4; ++n) {
        int gc = wcol + n * 16 + l15; lj[n] = labels[gc]; nj[n] = norms[gc];
    }
    int li[8]; float ni[8];
    #pragma unroll
    for (int m = 0; m < 2; ++m)
        #pragma unroll
        for (int r = 0; r < 4; ++r) {
            int gr = wrow + m * 16 + l4 * 4 + r;
            li[m * 4 + r] = labels[gr]; ni[m * 4 + r] = norms[gr];
        }

    float cp[4], cn[4];
    #pragma unroll
    for (int n = 0; n < 4; ++n) { cp[n] = 0.f; cn[n] = FINF; }

    #pragma unroll
    for (int m = 0; m < 2; ++m) {
        #pragma unroll
        for (int r = 0; r < 4; ++r) {
            float rp = 0.f, rn = FINF;
            #pragma unroll
            for (int n = 0; n < 4; ++n) {
                float sq = fmaxf(fmaf(-2.f, acc[m][n][r], ni[m * 4 + r] + nj[n]), 0.f);
                bool same = (li[m * 4 + r] == lj[n]);
                rp = same ? fmaxf(rp, sq) : rp;
                rn = same ? rn : fminf(rn, sq);
                cp[n] = same ? fmaxf(cp[n], sq) : cp[n];
                cn[n] = same ? cn[n] : fminf(cn[n], sq);
            }
            #pragma unroll
            for (int o = 8; o; o >>= 1) {
                rp = fmaxf(rp, __shfl_xor(rp, o));
                rn = fminf(rn, __shfl_xor(rn, o));
            }
            if (l15 == 0) {
                int gr = wrow + m * 16 + l4 * 4 + r;
                atomicMax(&hp[gr], __float_as_uint(rp));
                atomicMin(&hn[gr], __float_as_uint(rn));
            }
        }
    }
    #pragma unroll
    for (int n = 0; n < 4; ++n) {
        float p = cp[n], q = cn[n];
        p = fmaxf(p, __shfl_xor(p, 16)); q = fminf(q, __shfl_xor(q, 16));
        p = fmaxf(p, __shfl_xor(p, 32)); q = fminf(q, __shfl_xor(q, 32));
        if (l4 == 0) {
            int gc = wcol + n * 16 + l15;
            atomicMax(&hp[gc], __float_as_uint(p));
            atomicMin(&hn[gc], __float_as_uint(q));
        }
    }
}

// ---------------- fp32 fallback path (ws too small for Xh) ----------------
__global__ void norms_init_kernel(const float* __restrict__ X,
                                  float* __restrict__ norms,
                                  unsigned* __restrict__ hp, unsigned* __restrict__ hn) {
    int wave = threadIdx.x >> 6;
    int lane = threadIdx.x & 63;
    int row  = blockIdx.x * 4 + wave;
    const float4* xr = (const float4*)(X + (size_t)row * DIM);
    float4 a = xr[lane];
    float4 b = xr[lane + 64];
    float s = a.x*a.x + a.y*a.y + a.z*a.z + a.w*a.w
            + b.x*b.x + b.y*b.y + b.z*b.z + b.w*b.w;
    #pragma unroll
    for (int o = 32; o; o >>= 1) s += __shfl_xor(s, o);
    if (lane == 0) norms[row] = s;
    int g = blockIdx.x * 256 + threadIdx.x;
    if (g < NROWS) { hp[g] = 0u; hn[g] = 0x7f800000u; }
}

#define BK  32
#define PAD 68
__global__ __launch_bounds__(256) void dist_fp32_kernel(
        const float* __restrict__ X, const int* __restrict__ labels,
        const float* __restrict__ norms,
        unsigned* __restrict__ hp, unsigned* __restrict__ hn) {
    __shared__ __align__(16) float As[BK][PAD];
    __shared__ __align__(16) float Bs[BK][PAD];
    const int t  = threadIdx.x;
    const int tx = t & 15, ty = t >> 4;
    const int row0 = blockIdx.y * 64, col0 = blockIdx.x * 64;

    float acc[4][4] = {};
    for (int k0 = 0; k0 < DIM; k0 += BK) {
        #pragma unroll
        for (int l = 0; l < 2; ++l) {
            int idx = t + l * 256;
            int r = idx >> 3, fc = idx & 7;
            float4 va = *(const float4*)(X + (size_t)(row0 + r) * DIM + k0 + fc * 4);
            float4 vb = *(const float4*)(X + (size_t)(col0 + r) * DIM + k0 + fc * 4);
            As[fc*4+0][r] = va.x; As[fc*4+1][r] = va.y;
            As[fc*4+2][r] = va.z; As[fc*4+3][r] = va.w;
            Bs[fc*4+0][r] = vb.x; Bs[fc*4+1][r] = vb.y;
            Bs[fc*4+2][r] = vb.z; Bs[fc*4+3][r] = vb.w;
        }
        __syncthreads();
        #pragma unroll
        for (int kk = 0; kk < BK; ++kk) {
            float4 a = *(const float4*)&As[kk][ty * 4];
            float4 b = *(const float4*)&Bs[kk][tx * 4];
            float av[4] = {a.x, a.y, a.z, a.w};
            float bv[4] = {b.x, b.y, b.z, b.w};
            #pragma unroll
            for (int m = 0; m < 4; ++m)
                #pragma unroll
                for (int n = 0; n < 4; ++n)
                    acc[m][n] = fmaf(av[m], bv[n], acc[m][n]);
        }
        __syncthreads();
    }
    int li[4], lj[4]; float ni[4], nj[4];
    #pragma unroll
    for (int m = 0; m < 4; ++m) {
        int gi = row0 + ty * 4 + m; li[m] = labels[gi]; ni[m] = norms[gi];
    }
    #pragma unroll
    for (int n = 0; n < 4; ++n) {
        int gj = col0 + tx * 4 + n; lj[n] = labels[gj]; nj[n] = norms[gj];
    }
    #pragma unroll
    for (int m = 0; m < 4; ++m) {
        float pmax = 0.0f;
        float nmin = __uint_as_float(0x7f800000u);
        #pragma unroll
        for (int n = 0; n < 4; ++n) {
            float sq = fmaxf(ni[m] + nj[n] - 2.0f * acc[m][n], 0.0f);
            if (li[m] == lj[n]) pmax = fmaxf(pmax, sq);
            else                nmin = fminf(nmin, sq);
        }
        #pragma unroll
        for (int o = 8; o; o >>= 1) {
            pmax = fmaxf(pmax, __shfl_xor(pmax, o));
            nmin = fminf(nmin, __shfl_xor(nmin, o));
        }
        if (tx == 0) {
            int gi = row0 + ty * 4 + m;
            atomicMax(&hp[gi], __float_as_uint(pmax));
            atomicMin(&hn[gi], __float_as_uint(nmin));
        }
    }
}

// ---------------- finalize: hist in LDS + per-row loss + full reduce ----------------
__global__ __launch_bounds__(1024) void finalize_kernel(
        const unsigned* __restrict__ hp, const unsigned* __restrict__ hn,
        const int* __restrict__ labels, float* __restrict__ out) {
    __shared__ int hist[256];
    __shared__ float wsum[16];
    int t = threadIdx.x;
    if (t < 256) hist[t] = 0;
    __syncthreads();
    int4 lab = ((const int4*)labels)[t];
    atomicAdd(&hist[lab.x], 1); atomicAdd(&hist[lab.y], 1);
    atomicAdd(&hist[lab.z], 1); atomicAdd(&hist[lab.w], 1);
    __syncthreads();
    uint4 hp4 = ((const uint4*)hp)[t];
    uint4 hn4 = ((const uint4*)hn)[t];
    int      lv[4]  = {lab.x, lab.y, lab.z, lab.w};
    unsigned hpv[4] = {hp4.x, hp4.y, hp4.z, hp4.w};
    unsigned hnv[4] = {hn4.x, hn4.y, hn4.z, hn4.w};
    float v = 0.f;
    #pragma unroll
    for (int j = 0; j < 4; ++j) {
        float hpd = sqrtf(__uint_as_float(hpv[j]));
        float hnd = sqrtf(__uint_as_float(hnv[j]));   // may be +inf
        if (hist[lv[j]] > 1) v += fmaxf(hpd - hnd + MARGIN, 0.f);
    }
    #pragma unroll
    for (int o = 32; o; o >>= 1) v += __shfl_xor(v, o);
    int lane = t & 63, wv = t >> 6;
    if (lane == 0) wsum[wv] = v;
    __syncthreads();
    if (t == 0) {
        float s = 0.f;
        #pragma unroll
        for (int i = 0; i < 16; ++i) s += wsum[i];
        out[0] = s / (float)NROWS;
    }
}

extern "C" void kernel_launch(void* const* d_in, const int* in_sizes, int n_in,
                              void* d_out, int out_size, void* d_ws, size_t ws_size,
                              hipStream_t stream) {
    const float* X      = (const float*)d_in[0];
    const int*   labels = (const int*)d_in[1];
    float* ws = (float*)d_ws;
    // ws (floats): norms[4096] | hp[4096] | hn[4096] | pad -> 64KB | Xh (4MB)
    float*    norms = ws;
    unsigned* hp    = (unsigned*)(ws + 4096);
    unsigned* hn    = (unsigned*)(ws + 8192);
    f16*      Xh    = (f16*)((char*)d_ws + 65536);
    float*    out   = (float*)d_out;

    const size_t need = 65536 + (size_t)NROWS * DIM * sizeof(f16);

    if (ws_size >= need) {
        hipLaunchKernelGGL(prep_kernel,      dim3(NROWS/4), dim3(256), 0, stream,
                           X, norms, Xh, hp, hn);
        hipLaunchKernelGGL(mfma_dist_kernel, dim3(1056),    dim3(256), 0, stream,
                           Xh, labels, norms, hp, hn);
    } else {
        hipLaunchKernelGGL(norms_init_kernel, dim3(NROWS/4), dim3(256), 0, stream, X, norms, hp, hn);
        hipLaunchKernelGGL(dist_fp32_kernel,  dim3(64, 64),  dim3(256), 0, stream, X, labels, norms, hp, hn);
    }
    hipLaunchKernelGGL(finalize_kernel, dim3(1), dim3(1024), 0, stream, hp, hn, labels, out);
}

// Round 10
// 34.123 us; speedup vs baseline: 1.4778x; 1.1358x over previous
//
#include <hip/hip_runtime.h>

#define NROWS 4096
#define DIM   512
#define MARGIN 0.3f

typedef _Float16 f16;
typedef _Float16 f16x8 __attribute__((ext_vector_type(8)));
typedef float    f32x4 __attribute__((ext_vector_type(4)));

// ---------------- prep: norms + fp32->fp16 tiled convert + hp/hn init ----------------
// Xh layout: tile (R,K0), R=row/128 in [0,32), K0=k/32 in [0,16).
// Tile = 512 units of 16B: unit u = rg*64 + c*16 + r (rg=(row%128)/16, r=row%16)
// element (row, k=K0*32+c*8+j) at half index (tile*512+u)*8 + j.
__global__ void prep_kernel(const float* __restrict__ X,
                            float* __restrict__ norms, f16* __restrict__ Xh,
                            unsigned* __restrict__ hp, unsigned* __restrict__ hn) {
    int t = threadIdx.x;
    int wave = t >> 6, lane = t & 63;
    int row  = blockIdx.x * 4 + wave;
    const float4* p = (const float4*)(X + (size_t)row * DIM + lane * 8);
    float4 a = p[0], b = p[1];
    float s = a.x*a.x + a.y*a.y + a.z*a.z + a.w*a.w
            + b.x*b.x + b.y*b.y + b.z*b.z + b.w*b.w;
    #pragma unroll
    for (int o = 32; o; o >>= 1) s += __shfl_xor(s, o);
    if (lane == 0) norms[row] = s;

    f16x8 h;
    h[0] = (f16)a.x; h[1] = (f16)a.y; h[2] = (f16)a.z; h[3] = (f16)a.w;
    h[4] = (f16)b.x; h[5] = (f16)b.y; h[6] = (f16)b.z; h[7] = (f16)b.w;
    int K0 = lane >> 2, c = lane & 3;
    int R = row >> 7, rw = row & 127, rg = rw >> 4, r = rw & 15;
    size_t unit = (size_t)(R * 16 + K0) * 512 + rg * 64 + c * 16 + r;
    *(f16x8*)(Xh + unit * 8) = h;

    int g = blockIdx.x * 256 + t;
    if (g < NROWS) { hp[g] = 0u; hn[g] = 0x7f800000u; }
}

__device__ inline void gload_lds16(const f16* g, f16* l) {
    __builtin_amdgcn_global_load_lds(
        (const __attribute__((address_space(1))) void*)g,
        (__attribute__((address_space(3))) void*)l, 16, 0, 0);
}

// stage one 128x32 A-tile + B-tile pair into buf; wave w covers units [qb, qb+256)
__device__ inline void stage_tile(const f16* __restrict__ At, const f16* __restrict__ Bt,
                                  f16* buf, int qb, int lane) {
    const f16* base = (qb < 512) ? (At + (size_t)qb * 8) : (Bt + (size_t)(qb - 512) * 8);
    #pragma unroll
    for (int c2 = 0; c2 < 4; ++c2)
        gload_lds16(base + (size_t)(c2 * 64 + lane) * 8, buf + (size_t)(qb + c2 * 64) * 8);
}

// ---------------- MFMA fused GEMM + masked row/col max-min ----------------
// Lower-triangle grid (by <= bx); 128x128 tile, 4 waves. Triple-buffered LDS,
// ONE barrier per K-step, counted vmcnt (4 steady, 0 only at the last step).
// Round-6 structure verbatim + T5 setprio around the MFMA cluster.
__global__ __launch_bounds__(256, 3) void mfma_dist_kernel(
        const f16* __restrict__ Xh, const int* __restrict__ labels,
        const float* __restrict__ norms,
        unsigned* __restrict__ hp, unsigned* __restrict__ hn) {
    __shared__ __align__(16) f16 S[3 * 8192];

    const int t    = threadIdx.x;
    const int lane = t & 63, w = t >> 6;
    const int l15  = lane & 15, l4 = lane >> 4;

    // XCD chunk swizzle: 528 = 8 * 66 exactly -> bijective remap
    int bthw = blockIdx.x;
    int bt = (bthw & 7) * 66 + (bthw >> 3);

    // linear bt -> (by <= bx)
    int bx = (int)((sqrtf(8.0f * bt + 1.0f) - 1.0f) * 0.5f);
    while ((bx + 1) * (bx + 2) / 2 <= bt) ++bx;
    while (bx * (bx + 1) / 2 > bt) --bx;
    int by = bt - bx * (bx + 1) / 2;

    const int wr = w >> 1, wc = w & 1;
    const int qb = w * 256;

    const f16* Abase = Xh + (size_t)(by * 16) * 4096;
    const f16* Bbase = Xh + (size_t)(bx * 16) * 4096;

    f32x4 zero = {0.f, 0.f, 0.f, 0.f};
    f32x4 acc[4][4];
    #pragma unroll
    for (int m = 0; m < 4; ++m)
        #pragma unroll
        for (int n = 0; n < 4; ++n) acc[m][n] = zero;

    // prologue: tiles 0,1 in flight (8 loads/wave)
    stage_tile(Abase,        Bbase,        S,        qb, lane);
    stage_tile(Abase + 4096, Bbase + 4096, S + 8192, qb, lane);
    __builtin_amdgcn_sched_barrier(0);

    #pragma unroll
    for (int kt = 0; kt < 16; ++kt) {
        f16* cur = S + (kt % 3) * 8192;
        if (kt == 15) asm volatile("s_waitcnt vmcnt(0)" ::: "memory");
        else          asm volatile("s_waitcnt vmcnt(4)" ::: "memory");
        __builtin_amdgcn_sched_barrier(0);
        __builtin_amdgcn_s_barrier();      // all waves' tile-kt data in LDS
        __builtin_amdgcn_sched_barrier(0);

        if (kt + 2 < 16)                   // slot (kt+2)%3 consumed at step kt-1
            stage_tile(Abase + (size_t)(kt + 2) * 4096,
                       Bbase + (size_t)(kt + 2) * 4096,
                       S + ((kt + 2) % 3) * 8192, qb, lane);
        __builtin_amdgcn_sched_barrier(0);

        f16x8 af[4], bf[4];
        #pragma unroll
        for (int m = 0; m < 4; ++m)
            af[m] = *(const f16x8*)&cur[(size_t)((wr * 4 + m) * 64 + l4 * 16 + l15) * 8];
        #pragma unroll
        for (int n = 0; n < 4; ++n)
            bf[n] = *(const f16x8*)&cur[(size_t)(512 + (wc * 4 + n) * 64 + l4 * 16 + l15) * 8];
        __builtin_amdgcn_s_setprio(1);
        #pragma unroll
        for (int m = 0; m < 4; ++m)
            #pragma unroll
            for (int n = 0; n < 4; ++n)
                acc[m][n] = __builtin_amdgcn_mfma_f32_16x16x32_f16(af[m], bf[n], acc[m][n], 0, 0, 0);
        __builtin_amdgcn_s_setprio(0);
        __builtin_amdgcn_sched_barrier(0);
    }

    // ---- epilogue: sq = ni + nj - 2*dot, masked row & col reduce ----
    const int wrow = by * 128 + wr * 64;
    const int wcol = bx * 128 + wc * 64;
    const float FINF = __uint_as_float(0x7f800000u);

    int lj[4]; float nj[4];
    #pragma unroll
    for (int n = 0; n < 4; ++n) {
        int gc = wcol + n * 16 + l15; lj[n] = labels[gc]; nj[n] = norms[gc];
    }
    int li[16]; float ni[16];
    #pragma unroll
    for (int m = 0; m < 4; ++m)
        #pragma unroll
        for (int r = 0; r < 4; ++r) {
            int gr = wrow + m * 16 + l4 * 4 + r;
            li[m * 4 + r] = labels[gr]; ni[m * 4 + r] = norms[gr];
        }

    float cp[4], cn[4];
    #pragma unroll
    for (int n = 0; n < 4; ++n) { cp[n] = 0.f; cn[n] = FINF; }

    #pragma unroll
    for (int m = 0; m < 4; ++m) {
        #pragma unroll
        for (int r = 0; r < 4; ++r) {
            float rp = 0.f, rn = FINF;
            #pragma unroll
            for (int n = 0; n < 4; ++n) {
                float sq = fmaxf(fmaf(-2.f, acc[m][n][r], ni[m * 4 + r] + nj[n]), 0.f);
                bool same = (li[m * 4 + r] == lj[n]);
                rp = same ? fmaxf(rp, sq) : rp;
                rn = same ? rn : fminf(rn, sq);
                cp[n] = same ? fmaxf(cp[n], sq) : cp[n];
                cn[n] = same ? cn[n] : fminf(cn[n], sq);
            }
            #pragma unroll
            for (int o = 8; o; o >>= 1) {
                rp = fmaxf(rp, __shfl_xor(rp, o));
                rn = fminf(rn, __shfl_xor(rn, o));
            }
            if (l15 == 0) {
                int gr = wrow + m * 16 + l4 * 4 + r;
                atomicMax(&hp[gr], __float_as_uint(rp));
                atomicMin(&hn[gr], __float_as_uint(rn));
            }
        }
    }
    #pragma unroll
    for (int n = 0; n < 4; ++n) {
        float p = cp[n], q = cn[n];
        p = fmaxf(p, __shfl_xor(p, 16)); q = fminf(q, __shfl_xor(q, 16));
        p = fmaxf(p, __shfl_xor(p, 32)); q = fminf(q, __shfl_xor(q, 32));
        if (l4 == 0) {
            int gc = wcol + n * 16 + l15;
            atomicMax(&hp[gc], __float_as_uint(p));
            atomicMin(&hn[gc], __float_as_uint(q));
        }
    }
}

// ---------------- fp32 fallback path (ws too small for Xh) ----------------
__global__ void norms_init_kernel(const float* __restrict__ X,
                                  float* __restrict__ norms,
                                  unsigned* __restrict__ hp, unsigned* __restrict__ hn) {
    int wave = threadIdx.x >> 6;
    int lane = threadIdx.x & 63;
    int row  = blockIdx.x * 4 + wave;
    const float4* xr = (const float4*)(X + (size_t)row * DIM);
    float4 a = xr[lane];
    float4 b = xr[lane + 64];
    float s = a.x*a.x + a.y*a.y + a.z*a.z + a.w*a.w
            + b.x*b.x + b.y*b.y + b.z*b.z + b.w*b.w;
    #pragma unroll
    for (int o = 32; o; o >>= 1) s += __shfl_xor(s, o);
    if (lane == 0) norms[row] = s;
    int g = blockIdx.x * 256 + threadIdx.x;
    if (g < NROWS) { hp[g] = 0u; hn[g] = 0x7f800000u; }
}

#define BK  32
#define PAD 68
__global__ __launch_bounds__(256) void dist_fp32_kernel(
        const float* __restrict__ X, const int* __restrict__ labels,
        const float* __restrict__ norms,
        unsigned* __restrict__ hp, unsigned* __restrict__ hn) {
    __shared__ __align__(16) float As[BK][PAD];
    __shared__ __align__(16) float Bs[BK][PAD];
    const int t  = threadIdx.x;
    const int tx = t & 15, ty = t >> 4;
    const int row0 = blockIdx.y * 64, col0 = blockIdx.x * 64;

    float acc[4][4] = {};
    for (int k0 = 0; k0 < DIM; k0 += BK) {
        #pragma unroll
        for (int l = 0; l < 2; ++l) {
            int idx = t + l * 256;
            int r = idx >> 3, fc = idx & 7;
            float4 va = *(const float4*)(X + (size_t)(row0 + r) * DIM + k0 + fc * 4);
            float4 vb = *(const float4*)(X + (size_t)(col0 + r) * DIM + k0 + fc * 4);
            As[fc*4+0][r] = va.x; As[fc*4+1][r] = va.y;
            As[fc*4+2][r] = va.z; As[fc*4+3][r] = va.w;
            Bs[fc*4+0][r] = vb.x; Bs[fc*4+1][r] = vb.y;
            Bs[fc*4+2][r] = vb.z; Bs[fc*4+3][r] = vb.w;
        }
        __syncthreads();
        #pragma unroll
        for (int kk = 0; kk < BK; ++kk) {
            float4 a = *(const float4*)&As[kk][ty * 4];
            float4 b = *(const float4*)&Bs[kk][tx * 4];
            float av[4] = {a.x, a.y, a.z, a.w};
            float bv[4] = {b.x, b.y, b.z, b.w};
            #pragma unroll
            for (int m = 0; m < 4; ++m)
                #pragma unroll
                for (int n = 0; n < 4; ++n)
                    acc[m][n] = fmaf(av[m], bv[n], acc[m][n]);
        }
        __syncthreads();
    }
    int li[4], lj[4]; float ni[4], nj[4];
    #pragma unroll
    for (int m = 0; m < 4; ++m) {
        int gi = row0 + ty * 4 + m; li[m] = labels[gi]; ni[m] = norms[gi];
    }
    #pragma unroll
    for (int n = 0; n < 4; ++n) {
        int gj = col0 + tx * 4 + n; lj[n] = labels[gj]; nj[n] = norms[gj];
    }
    #pragma unroll
    for (int m = 0; m < 4; ++m) {
        float pmax = 0.0f;
        float nmin = __uint_as_float(0x7f800000u);
        #pragma unroll
        for (int n = 0; n < 4; ++n) {
            float sq = fmaxf(ni[m] + nj[n] - 2.0f * acc[m][n], 0.0f);
            if (li[m] == lj[n]) pmax = fmaxf(pmax, sq);
            else                nmin = fminf(nmin, sq);
        }
        #pragma unroll
        for (int o = 8; o; o >>= 1) {
            pmax = fmaxf(pmax, __shfl_xor(pmax, o));
            nmin = fminf(nmin, __shfl_xor(nmin, o));
        }
        if (tx == 0) {
            int gi = row0 + ty * 4 + m;
            atomicMax(&hp[gi], __float_as_uint(pmax));
            atomicMin(&hn[gi], __float_as_uint(nmin));
        }
    }
}

// ---------------- finalize: hist in LDS + per-row loss + full reduce ----------------
__global__ __launch_bounds__(1024) void finalize_kernel(
        const unsigned* __restrict__ hp, const unsigned* __restrict__ hn,
        const int* __restrict__ labels, float* __restrict__ out) {
    __shared__ int hist[256];
    __shared__ float wsum[16];
    int t = threadIdx.x;
    if (t < 256) hist[t] = 0;
    __syncthreads();
    int4 lab = ((const int4*)labels)[t];
    atomicAdd(&hist[lab.x], 1); atomicAdd(&hist[lab.y], 1);
    atomicAdd(&hist[lab.z], 1); atomicAdd(&hist[lab.w], 1);
    __syncthreads();
    uint4 hp4 = ((const uint4*)hp)[t];
    uint4 hn4 = ((const uint4*)hn)[t];
    int      lv[4]  = {lab.x, lab.y, lab.z, lab.w};
    unsigned hpv[4] = {hp4.x, hp4.y, hp4.z, hp4.w};
    unsigned hnv[4] = {hn4.x, hn4.y, hn4.z, hn4.w};
    float v = 0.f;
    #pragma unroll
    for (int j = 0; j < 4; ++j) {
        float hpd = sqrtf(__uint_as_float(hpv[j]));
        float hnd = sqrtf(__uint_as_float(hnv[j]));   // may be +inf
        if (hist[lv[j]] > 1) v += fmaxf(hpd - hnd + MARGIN, 0.f);
    }
    #pragma unroll
    for (int o = 32; o; o >>= 1) v += __shfl_xor(v, o);
    int lane = t & 63, wv = t >> 6;
    if (lane == 0) wsum[wv] = v;
    __syncthreads();
    if (t == 0) {
        float s = 0.f;
        #pragma unroll
        for (int i = 0; i < 16; ++i) s += wsum[i];
        out[0] = s / (float)NROWS;
    }
}

extern "C" void kernel_launch(void* const* d_in, const int* in_sizes, int n_in,
                              void* d_out, int out_size, void* d_ws, size_t ws_size,
                              hipStream_t stream) {
    const float* X      = (const float*)d_in[0];
    const int*   labels = (const int*)d_in[1];
    float* ws = (float*)d_ws;
    // ws (floats): norms[4096] | hp[4096] | hn[4096] | pad -> 64KB | Xh (4MB)
    float*    norms = ws;
    unsigned* hp    = (unsigned*)(ws + 4096);
    unsigned* hn    = (unsigned*)(ws + 8192);
    f16*      Xh    = (f16*)((char*)d_ws + 65536);
    float*    out   = (float*)d_out;

    const size_t need = 65536 + (size_t)NROWS * DIM * sizeof(f16);

    if (ws_size >= need) {
        hipLaunchKernelGGL(prep_kernel,      dim3(NROWS/4), dim3(256), 0, stream,
                           X, norms, Xh, hp, hn);
        hipLaunchKernelGGL(mfma_dist_kernel, dim3(528),     dim3(256), 0, stream,
                           Xh, labels, norms, hp, hn);
    } else {
        hipLaunchKernelGGL(norms_init_kernel, dim3(NROWS/4), dim3(256), 0, stream, X, norms, hp, hn);
        hipLaunchKernelGGL(dist_fp32_kernel,  dim3(64, 64),  dim3(256), 0, stream, X, labels, norms, hp, hn);
    }
    hipLaunchKernelGGL(finalize_kernel, dim3(1), dim3(1024), 0, stream, hp, hn, labels, out);
}